// Round 11
// baseline (95.886 us; speedup 1.0000x reference)
//
#include <hip/hip_runtime.h>
#include <hip/hip_bf16.h>
#include <stdint.h>

typedef __attribute__((ext_vector_type(8))) short  s16x8;
typedef __attribute__((ext_vector_type(8))) __bf16 bf16x8;
typedef __attribute__((ext_vector_type(4))) float  f32x4;

#define N_ROWS  32768   // 64 * 512
#define N_CODES 1024
#define DIM     512
#define BK      32      // K-tile (elements)
#define NT      (DIM / BK)   // 16 K-steps

static __device__ __forceinline__ short f2bf(float f) {
    unsigned u = __float_as_uint(f);
    u += 0x7fffu + ((u >> 16) & 1u);   // round-to-nearest-even
    return (short)(u >> 16);
}

typedef const __attribute__((address_space(1))) uint32_t guint;
typedef __attribute__((address_space(3))) uint32_t luint;
static __device__ __forceinline__ void gl_lds16(const short* g, short* l) {
    __builtin_amdgcn_global_load_lds((guint*)g, (luint*)l, 16, 0, 0);
}
static __device__ __forceinline__ void gl_lds16f(const float* g, float* l) {
    __builtin_amdgcn_global_load_lds((guint*)g, (luint*)l, 16, 0, 0);
}

// ---------------- K0: convert W to bf16 + codebook norms ----------------
__global__ void __launch_bounds__(256)
convertW(const float* __restrict__ W, short* __restrict__ Wb,
         float* __restrict__ wnorm) {
    const int lane = threadIdx.x & 63;
    const int code = blockIdx.x * 4 + (threadIdx.x >> 6);
    const float4* wp = (const float4*)(W + (size_t)code * DIM + lane * 8);
    float4 a = wp[0], b = wp[1];
    s16x8 v = { f2bf(a.x), f2bf(a.y), f2bf(a.z), f2bf(a.w),
                f2bf(b.x), f2bf(b.y), f2bf(b.z), f2bf(b.w) };
    *(s16x8*)(Wb + (size_t)code * DIM + lane * 8) = v;
    float s = a.x*a.x + a.y*a.y + a.z*a.z + a.w*a.w
            + b.x*b.x + b.y*b.y + b.z*b.z + b.w*b.w;
    #pragma unroll
    for (int d = 1; d < 64; d <<= 1) s += __shfl_xor(s, d);
    if (lane == 0) wnorm[code] = s;
}

// ---------------- K1: MFMA GEMM, A from f32 X (in-register cast) + xnorm ----------------
// 128x128 tile, BK=32. A staged as f32 (row=128B=8 slots of 16B): 8-slot XOR
// swizzle (source slot s^(row&7), linear gl_lds dest, read (2kg|b)^(lr&7))
// -> <=2-way bank aliasing (free). Frags cast f32->bf16 in-register with the
// same RNE f2bf as before -> scores identical to the Xb path. B path is the
// R9-verified bf16 layout (4-slot XOR, 0 conflicts). Triple-buffer + counted
// vmcnt(6). wc==0 waves accumulate exact-f32 row norms; colBlk==0 writes.
// XCD row-chunk swizzle unchanged.
__global__ void __launch_bounds__(256)
gemm_argmin(const float* __restrict__ X, const short* __restrict__ Wb,
            const float* __restrict__ wnorm, uint32_t* __restrict__ keys,
            float* __restrict__ xnorm) {
    __shared__ __align__(16) float Asf[3][128 * BK];  // 48 KB
    __shared__ __align__(16) short Bs[3][128 * BK];   // 24 KB

    const int tid  = threadIdx.x;
    const int lane = tid & 63;
    const int wave = tid >> 6;
    const int wr = wave >> 1, wc = wave & 1;
    const int lr = lane & 15, kg = lane >> 4;

    const int bid = blockIdx.x;
    const int colBase = ((bid >> 3) & 7) * 128;
    const int rowBase = ((bid & 7) * 32 + (bid >> 6)) * 128;

    // A staging (f32): instr j covers rows wave*32 + j*8 + (lane>>3), slot
    // lane&7; source slot pre-swizzled by row&7 = lane>>3. Dest linear.
    const float* aS = X + (size_t)(rowBase + wave*32 + (lane >> 3)) * DIM
                        + ((lane & 7) ^ (lane >> 3)) * 4;
    // B staging (bf16): R9-verified. rows tid>>2 (+64), slot tid&3,
    // source slot pre-swizzled by (row>>1)&3 = (tid>>3)&3.
    const int ssw = ((tid & 3) ^ ((tid >> 3) & 3)) * 8;
    const short* bS = Wb + (size_t)(colBase + (tid >> 2)) * DIM + ssw;

#define STAGE(buf, t) do {                                                    \
    gl_lds16f(aS            + (t) * BK, &Asf[buf][wave*1024 +       lane*4]); \
    gl_lds16f(aS +  8*DIM   + (t) * BK, &Asf[buf][wave*1024 + 256 + lane*4]); \
    gl_lds16f(aS + 16*DIM   + (t) * BK, &Asf[buf][wave*1024 + 512 + lane*4]); \
    gl_lds16f(aS + 24*DIM   + (t) * BK, &Asf[buf][wave*1024 + 768 + lane*4]); \
    gl_lds16(bS + (t) * BK,           &Bs[buf][tid * 8]);                     \
    gl_lds16(bS + 64*DIM + (t) * BK,  &Bs[buf][tid * 8 + 2048]);              \
  } while (0)

    f32x4 acc[4][4];
    #pragma unroll
    for (int m = 0; m < 4; ++m)
        #pragma unroll
        for (int n = 0; n < 4; ++n) acc[m][n] = (f32x4)0.f;
    float nrm[4] = {0.f, 0.f, 0.f, 0.f};

    const int fqB = (kg ^ ((lr >> 1) & 3)) * 8;       // B read slot (shorts)
    const int pa0 = ((2*kg)     ^ (lr & 7)) * 4;      // A read slots (floats)
    const int pa1 = ((2*kg + 1) ^ (lr & 7)) * 4;

    STAGE(0, 0);
    STAGE(1, 1);
    asm volatile("s_waitcnt vmcnt(6)" ::: "memory");
    __builtin_amdgcn_s_barrier();

    #pragma unroll
    for (int t = 0; t < NT; ++t) {
        const int cur = t % 3;
        if (t + 2 < NT) STAGE((t + 2) % 3, t + 2);
        bf16x8 aF[4], bF[4];
        #pragma unroll
        for (int m = 0; m < 4; ++m) {
            const float* rp = &Asf[cur][(wr*64 + m*16 + lr) * BK];
            float4 f0 = *(const float4*)(rp + pa0);
            float4 f1 = *(const float4*)(rp + pa1);
            if (wc == 0)
                nrm[m] += f0.x*f0.x + f0.y*f0.y + f0.z*f0.z + f0.w*f0.w
                        + f1.x*f1.x + f1.y*f1.y + f1.z*f1.z + f1.w*f1.w;
            s16x8 av = { f2bf(f0.x), f2bf(f0.y), f2bf(f0.z), f2bf(f0.w),
                         f2bf(f1.x), f2bf(f1.y), f2bf(f1.z), f2bf(f1.w) };
            aF[m] = __builtin_bit_cast(bf16x8, av);
        }
        #pragma unroll
        for (int n = 0; n < 4; ++n)
            bF[n] = __builtin_bit_cast(bf16x8,
                *(const s16x8*)&Bs[cur][(wc*64 + n*16 + lr) * BK + fqB]);
        #pragma unroll
        for (int m = 0; m < 4; ++m)
            #pragma unroll
            for (int n = 0; n < 4; ++n)
                acc[m][n] = __builtin_amdgcn_mfma_f32_16x16x32_bf16(
                    aF[m], bF[n], acc[m][n], 0, 0, 0);
        if (t < NT - 2) {
            asm volatile("s_waitcnt vmcnt(6)" ::: "memory");
            __builtin_amdgcn_s_barrier();
        } else if (t == NT - 2) {
            asm volatile("s_waitcnt vmcnt(0)" ::: "memory");
            __builtin_amdgcn_s_barrier();
        }
    }
#undef STAGE

    // xnorm: exact f32 row norms; kg-lanes hold disjoint k-partials.
    if (colBase == 0 && wc == 0) {
        #pragma unroll
        for (int m = 0; m < 4; ++m) {
            float nv = nrm[m];
            nv += __shfl_xor(nv, 16);
            nv += __shfl_xor(nv, 32);
            if (lane < 16)
                xnorm[rowBase + wr*64 + m*16 + lane] = nv;
        }
    }

    // Argmin epilogue: packed sortable u32, col in low 10 bits.
    float wn[4]; int wcol[4];
    #pragma unroll
    for (int n = 0; n < 4; ++n) {
        wcol[n] = colBase + wc*64 + n*16 + lr;
        wn[n] = wnorm[wcol[n]];
    }
    const int chunk = (colBase >> 6) + wc;   // 0..15
    #pragma unroll
    for (int m = 0; m < 4; ++m) {
        #pragma unroll
        for (int r = 0; r < 4; ++r) {
            uint32_t best = 0xFFFFFFFFu;
            #pragma unroll
            for (int n = 0; n < 4; ++n) {
                float sc = wn[n] - 2.0f * acc[m][n][r];
                uint32_t u = __float_as_uint(sc);
                u = (u & 0x80000000u) ? ~u : (u | 0x80000000u);  // sortable
                uint32_t key = (u & ~1023u) | (uint32_t)wcol[n];
                best = min(best, key);
            }
            #pragma unroll
            for (int d = 1; d < 16; d <<= 1)
                best = min(best, (uint32_t)__shfl_xor((int)best, d));
            if (lr == 0) {
                const int row = rowBase + wr*64 + m*16 + kg*4 + r;
                keys[(size_t)row * 16 + chunk] = best;
            }
        }
    }
}

// ---------------- K2: min over 16 chunk keys + xnorm -> block partial ----------------
__global__ void __launch_bounds__(256)
reduce_loss(const uint32_t* __restrict__ keys, const float* __restrict__ xnorm,
            float* __restrict__ partial) {
    __shared__ float sm[256];
    const int row = blockIdx.x * 256 + threadIdx.x;
    const uint4* kp = (const uint4*)(keys + (size_t)row * 16);
    uint4 k0 = kp[0], k1 = kp[1], k2 = kp[2], k3 = kp[3];
    uint32_t mk = min(min(min(k0.x, k0.y), min(k0.z, k0.w)),
                      min(min(k1.x, k1.y), min(k1.z, k1.w)));
    mk = min(mk, min(min(min(k2.x, k2.y), min(k2.z, k2.w)),
                     min(min(k3.x, k3.y), min(k3.z, k3.w))));
    uint32_t sb = mk & ~1023u;
    float sc = (sb & 0x80000000u) ? __uint_as_float(sb ^ 0x80000000u)
                                  : __uint_as_float(~sb);
    sm[threadIdx.x] = xnorm[row] + sc;   // ||x||^2 + (||w||^2 - 2 x.w)
    __syncthreads();
    for (int st = 128; st > 0; st >>= 1) {
        if (threadIdx.x < st) sm[threadIdx.x] += sm[threadIdx.x + st];
        __syncthreads();
    }
    if (threadIdx.x == 0) partial[blockIdx.x] = sm[0];
}

// ---------------- K3: final mean over 128 partials (double accum) ----------------
__global__ void __launch_bounds__(128)
finalize(const float* __restrict__ partial, float* __restrict__ out) {
    __shared__ double sm[128];
    sm[threadIdx.x] = (double)partial[threadIdx.x];
    __syncthreads();
    for (int st = 64; st > 0; st >>= 1) {
        if (threadIdx.x < st) sm[threadIdx.x] += sm[threadIdx.x + st];
        __syncthreads();
    }
    if (threadIdx.x == 0)
        out[0] = (float)(sm[0] / (double)((size_t)N_ROWS * DIM));
}

extern "C" void kernel_launch(void* const* d_in, const int* in_sizes, int n_in,
                              void* d_out, int out_size, void* d_ws, size_t ws_size,
                              hipStream_t stream) {
    const float* X = (const float*)d_in[0];   // [32768][512]
    const float* W = (const float*)d_in[1];   // [1024][512]
    char* ws = (char*)d_ws;
    short*    Wb      = (short*)ws;                    // 1 MB @ 0
    float*    wnorm   = (float*)(ws + 1048576);        // 4 KB
    float*    xnorm   = (float*)(ws + 1052672);        // 128 KB
    uint32_t* keys    = (uint32_t*)(ws + 1183744);     // 2 MB
    float*    partial = (float*)(ws + 3280896);        // 512 B
    float*    out     = (float*)d_out;

    convertW<<<N_CODES / 4, 256, 0, stream>>>(W, Wb, wnorm);
    gemm_argmin<<<2048, 256, 0, stream>>>(X, Wb, wnorm, keys, xnorm);
    reduce_loss<<<N_ROWS / 256, 256, 0, stream>>>(keys, xnorm, partial);
    finalize<<<1, 128, 0, stream>>>(partial, out);
}

// Round 12
// 81.226 us; speedup vs baseline: 1.1805x; 1.1805x over previous
//
#include <hip/hip_runtime.h>
#include <hip/hip_bf16.h>
#include <stdint.h>

typedef __attribute__((ext_vector_type(8))) short  s16x8;
typedef __attribute__((ext_vector_type(8))) __bf16 bf16x8;
typedef __attribute__((ext_vector_type(4))) float  f32x4;

#define N_ROWS  32768   // 64 * 512
#define N_CODES 1024
#define DIM     512
#define BK      32      // K-tile (shorts)
#define NT      (DIM / BK)   // 16 K-steps

static __device__ __forceinline__ short f2bf(float f) {
    unsigned u = __float_as_uint(f);
    u += 0x7fffu + ((u >> 16) & 1u);   // round-to-nearest-even
    return (short)(u >> 16);
}

typedef const __attribute__((address_space(1))) uint32_t guint;
typedef __attribute__((address_space(3))) uint32_t luint;
static __device__ __forceinline__ void gl_lds16(const short* g, short* l) {
    __builtin_amdgcn_global_load_lds((guint*)g, (luint*)l, 16, 0, 0);
}

// ---------------- K0a: convert X to bf16 + row norms ----------------
__global__ void __launch_bounds__(256)
convertX(const float* __restrict__ X, short* __restrict__ Xb,
         float* __restrict__ xnorm) {
    const int lane = threadIdx.x & 63;
    const int row  = blockIdx.x * 4 + (threadIdx.x >> 6);
    const float4* xp = (const float4*)(X + (size_t)row * DIM + lane * 8);
    float4 a = xp[0], b = xp[1];
    s16x8 v = { f2bf(a.x), f2bf(a.y), f2bf(a.z), f2bf(a.w),
                f2bf(b.x), f2bf(b.y), f2bf(b.z), f2bf(b.w) };
    *(s16x8*)(Xb + (size_t)row * DIM + lane * 8) = v;
    float s = a.x*a.x + a.y*a.y + a.z*a.z + a.w*a.w
            + b.x*b.x + b.y*b.y + b.z*b.z + b.w*b.w;
    #pragma unroll
    for (int d = 1; d < 64; d <<= 1) s += __shfl_xor(s, d);
    if (lane == 0) xnorm[row] = s;
}

// ---------------- K0b: convert W to bf16 + codebook norms ----------------
__global__ void __launch_bounds__(256)
convertW(const float* __restrict__ W, short* __restrict__ Wb,
         float* __restrict__ wnorm) {
    const int lane = threadIdx.x & 63;
    const int code = blockIdx.x * 4 + (threadIdx.x >> 6);
    const float4* wp = (const float4*)(W + (size_t)code * DIM + lane * 8);
    float4 a = wp[0], b = wp[1];
    s16x8 v = { f2bf(a.x), f2bf(a.y), f2bf(a.z), f2bf(a.w),
                f2bf(b.x), f2bf(b.y), f2bf(b.z), f2bf(b.w) };
    *(s16x8*)(Wb + (size_t)code * DIM + lane * 8) = v;
    float s = a.x*a.x + a.y*a.y + a.z*a.z + a.w*a.w
            + b.x*b.x + b.y*b.y + b.z*b.z + b.w*b.w;
    #pragma unroll
    for (int d = 1; d < 64; d <<= 1) s += __shfl_xor(s, d);
    if (lane == 0) wnorm[code] = s;
}

// ---------------- K1: barrier-free single-wave MFMA GEMM + argmin ----------------
// 1 wave per block, 64x128 output tile, BK=32, single 12KB LDS buffer.
// NO barriers: wave-synchronous staging via own vmcnt/lgkmcnt -> 8 fully
// INDEPENDENT waves/CU whose stalls decorrelate (the 2-phase multi-wave
// structure pinned at ~650TF with all pipes <50% busy = correlated-stall
// latency exposure). Verified pieces unchanged: 0-conflict read form
// (16 rows/instr, 4-slot XOR both-sides), gl_lds linear dest + pre-swizzled
// source, XCD row-chunk swizzle, packed-key argmin.
__global__ void __launch_bounds__(64, 2)
gemm_argmin(const short* __restrict__ Xb, const short* __restrict__ Wb,
            const float* __restrict__ wnorm, uint32_t* __restrict__ keys) {
    __shared__ __align__(16) short As[64 * BK];    // 4 KB
    __shared__ __align__(16) short Bs[128 * BK];   // 8 KB

    const int lane = threadIdx.x;
    const int lr = lane & 15, kg = lane >> 4;

    // bid = xcd + 8*colBlk(0..7) + 64*rowLocal(0..63); grid 4096.
    // XCD x owns Xb rows [x*4096, x*4096+4096) = 4MB slice (L2-resident).
    const int bid = blockIdx.x;
    const int colBase = ((bid >> 3) & 7) * 128;
    const int rowBase = ((bid & 7) * 64 + (bid >> 6)) * 64;

    // staging: instr j covers 16 rows (lane>>2)+16j, phys slot lane&3;
    // source k-slot pre-swizzled by (row>>1)&3 = (lane>>3)&3 (16j even).
    const int ssw = ((lane & 3) ^ ((lane >> 3) & 3)) * 8;
    const short* aS = Xb + (size_t)(rowBase + (lane >> 2)) * DIM + ssw;
    const short* bS = Wb + (size_t)(colBase + (lane >> 2)) * DIM + ssw;

#define STAGE(t) do {                                                         \
    _Pragma("unroll")                                                         \
    for (int j = 0; j < 4; ++j)                                               \
        gl_lds16(aS + (size_t)(j * 16) * DIM + (t) * BK, &As[j*512 + lane*8]);\
    _Pragma("unroll")                                                         \
    for (int j = 0; j < 8; ++j)                                               \
        gl_lds16(bS + (size_t)(j * 16) * DIM + (t) * BK, &Bs[j*512 + lane*8]);\
  } while (0)

    f32x4 acc[4][8];
    #pragma unroll
    for (int m = 0; m < 4; ++m)
        #pragma unroll
        for (int n = 0; n < 8; ++n) acc[m][n] = (f32x4)0.f;

    const int fq = (kg ^ ((lr >> 1) & 3)) * 8;   // swizzled read slot (shorts)

    STAGE(0);
    asm volatile("s_waitcnt vmcnt(0)" ::: "memory");

    for (int t = 0; t < NT; ++t) {
        bf16x8 aF[4], bF[8];
        #pragma unroll
        for (int m = 0; m < 4; ++m)
            aF[m] = __builtin_bit_cast(bf16x8,
                *(const s16x8*)&As[(m*16 + lr) * BK + fq]);
        #pragma unroll
        for (int n = 0; n < 8; ++n)
            bF[n] = __builtin_bit_cast(bf16x8,
                *(const s16x8*)&Bs[(n*16 + lr) * BK + fq]);
        if (t < NT - 1) {
            // all reads retired to VGPRs before DMA may overwrite the buffer
            asm volatile("s_waitcnt lgkmcnt(0)" ::: "memory");
            __builtin_amdgcn_sched_barrier(0);
            STAGE(t + 1);                      // overlaps with MFMA below
        }
        #pragma unroll
        for (int m = 0; m < 4; ++m)
            #pragma unroll
            for (int n = 0; n < 8; ++n)
                acc[m][n] = __builtin_amdgcn_mfma_f32_16x16x32_bf16(
                    aF[m], bF[n], acc[m][n], 0, 0, 0);
        if (t < NT - 1)
            asm volatile("s_waitcnt vmcnt(0)" ::: "memory");  // staging landed
    }
#undef STAGE

    // Epilogue: score = wnorm[col] - 2*dot, packed sortable u32 (col in low
    // 10 bits, tie-break = lowest col). 2 key-chunks of 4 n-frags each.
    float wn[8]; int wcol[8];
    #pragma unroll
    for (int n = 0; n < 8; ++n) {
        wcol[n] = colBase + n*16 + lr;
        wn[n] = wnorm[wcol[n]];
    }
    #pragma unroll
    for (int m = 0; m < 4; ++m) {
        #pragma unroll
        for (int r = 0; r < 4; ++r) {
            #pragma unroll
            for (int g = 0; g < 2; ++g) {
                uint32_t best = 0xFFFFFFFFu;
                #pragma unroll
                for (int j = 0; j < 4; ++j) {
                    const int n = g * 4 + j;
                    float sc = wn[n] - 2.0f * acc[m][n][r];
                    uint32_t u = __float_as_uint(sc);
                    u = (u & 0x80000000u) ? ~u : (u | 0x80000000u);  // sortable
                    uint32_t key = (u & ~1023u) | (uint32_t)wcol[n];
                    best = min(best, key);
                }
                #pragma unroll
                for (int d = 1; d < 16; d <<= 1)
                    best = min(best, (uint32_t)__shfl_xor((int)best, d));
                if (lr == 0) {
                    const int row = rowBase + m*16 + kg*4 + r;
                    keys[(size_t)row * 16 + (colBase >> 6) + g] = best;
                }
            }
        }
    }
}

// ---------------- K2: min over 16 chunk keys + xnorm -> block partial ----------------
__global__ void __launch_bounds__(256)
reduce_loss(const uint32_t* __restrict__ keys, const float* __restrict__ xnorm,
            float* __restrict__ partial) {
    __shared__ float sm[256];
    const int row = blockIdx.x * 256 + threadIdx.x;
    const uint4* kp = (const uint4*)(keys + (size_t)row * 16);
    uint4 k0 = kp[0], k1 = kp[1], k2 = kp[2], k3 = kp[3];
    uint32_t mk = min(min(min(k0.x, k0.y), min(k0.z, k0.w)),
                      min(min(k1.x, k1.y), min(k1.z, k1.w)));
    mk = min(mk, min(min(min(k2.x, k2.y), min(k2.z, k2.w)),
                     min(min(k3.x, k3.y), min(k3.z, k3.w))));
    uint32_t sb = mk & ~1023u;
    float sc = (sb & 0x80000000u) ? __uint_as_float(sb ^ 0x80000000u)
                                  : __uint_as_float(~sb);
    sm[threadIdx.x] = xnorm[row] + sc;   // ||x||^2 + (||w||^2 - 2 x.w)
    __syncthreads();
    for (int st = 128; st > 0; st >>= 1) {
        if (threadIdx.x < st) sm[threadIdx.x] += sm[threadIdx.x + st];
        __syncthreads();
    }
    if (threadIdx.x == 0) partial[blockIdx.x] = sm[0];
}

// ---------------- K3: final mean over 128 partials (double accum) ----------------
__global__ void __launch_bounds__(128)
finalize(const float* __restrict__ partial, float* __restrict__ out) {
    __shared__ double sm[128];
    sm[threadIdx.x] = (double)partial[threadIdx.x];
    __syncthreads();
    for (int st = 64; st > 0; st >>= 1) {
        if (threadIdx.x < st) sm[threadIdx.x] += sm[threadIdx.x + st];
        __syncthreads();
    }
    if (threadIdx.x == 0)
        out[0] = (float)(sm[0] / (double)((size_t)N_ROWS * DIM));
}

extern "C" void kernel_launch(void* const* d_in, const int* in_sizes, int n_in,
                              void* d_out, int out_size, void* d_ws, size_t ws_size,
                              hipStream_t stream) {
    const float* X = (const float*)d_in[0];   // [32768][512]
    const float* W = (const float*)d_in[1];   // [1024][512]
    char* ws = (char*)d_ws;
    short*    Xb      = (short*)ws;                          // 32 MB @ 0
    short*    Wb      = (short*)(ws + 33554432);             // 1 MB
    float*    wnorm   = (float*)(ws + 34603008);             // 4 KB
    float*    xnorm   = (float*)(ws + 34607104);             // 128 KB
    uint32_t* keys    = (uint32_t*)(ws + 34738176);          // 2 MB
    float*    partial = (float*)(ws + 36835328);             // 512 B
    float*    out     = (float*)d_out;

    convertX<<<N_ROWS / 4, 256, 0, stream>>>(X, Xb, xnorm);
    convertW<<<N_CODES / 4, 256, 0, stream>>>(W, Wb, wnorm);
    gemm_argmin<<<4096, 64, 0, stream>>>(Xb, Wb, wnorm, keys);
    reduce_loss<<<N_ROWS / 256, 256, 0, stream>>>(keys, xnorm, partial);
    finalize<<<1, 128, 0, stream>>>(partial, out);
}

// Round 13
// 76.630 us; speedup vs baseline: 1.2513x; 1.0600x over previous
//
#include <hip/hip_runtime.h>
#include <hip/hip_bf16.h>
#include <stdint.h>

typedef __attribute__((ext_vector_type(8))) short  s16x8;
typedef __attribute__((ext_vector_type(8))) __bf16 bf16x8;
typedef __attribute__((ext_vector_type(4))) float  f32x4;

#define N_ROWS  32768   // 64 * 512
#define N_CODES 1024
#define DIM     512
#define BK      64
#define NT      (DIM / BK)   // 8 K-tiles

static __device__ __forceinline__ short f2bf(float f) {
    unsigned u = __float_as_uint(f);
    u += 0x7fffu + ((u >> 16) & 1u);   // round-to-nearest-even
    return (short)(u >> 16);
}

typedef const __attribute__((address_space(1))) uint32_t guint;
typedef __attribute__((address_space(3))) uint32_t luint;
static __device__ __forceinline__ void gl_lds16(const short* g, short* l) {
    __builtin_amdgcn_global_load_lds((guint*)g, (luint*)l, 16, 0, 0);
}

// ---------------- K0a: convert X to bf16 + row norms ----------------
__global__ void __launch_bounds__(256)
convertX(const float* __restrict__ X, short* __restrict__ Xb,
         float* __restrict__ xnorm) {
    const int lane = threadIdx.x & 63;
    const int row  = blockIdx.x * 4 + (threadIdx.x >> 6);
    const float4* xp = (const float4*)(X + (size_t)row * DIM + lane * 8);
    float4 a = xp[0], b = xp[1];
    s16x8 v = { f2bf(a.x), f2bf(a.y), f2bf(a.z), f2bf(a.w),
                f2bf(b.x), f2bf(b.y), f2bf(b.z), f2bf(b.w) };
    *(s16x8*)(Xb + (size_t)row * DIM + lane * 8) = v;
    float s = a.x*a.x + a.y*a.y + a.z*a.z + a.w*a.w
            + b.x*b.x + b.y*b.y + b.z*b.z + b.w*b.w;
    #pragma unroll
    for (int d = 1; d < 64; d <<= 1) s += __shfl_xor(s, d);
    if (lane == 0) xnorm[row] = s;
}

// ---------------- K0b: convert W to bf16 + codebook norms ----------------
__global__ void __launch_bounds__(256)
convertW(const float* __restrict__ W, short* __restrict__ Wb,
         float* __restrict__ wnorm) {
    const int lane = threadIdx.x & 63;
    const int code = blockIdx.x * 4 + (threadIdx.x >> 6);
    const float4* wp = (const float4*)(W + (size_t)code * DIM + lane * 8);
    float4 a = wp[0], b = wp[1];
    s16x8 v = { f2bf(a.x), f2bf(a.y), f2bf(a.z), f2bf(a.w),
                f2bf(b.x), f2bf(b.y), f2bf(b.z), f2bf(b.w) };
    *(s16x8*)(Wb + (size_t)code * DIM + lane * 8) = v;
    float s = a.x*a.x + a.y*a.y + a.z*a.z + a.w*a.w
            + b.x*b.x + b.y*b.y + b.z*b.z + b.w*b.w;
    #pragma unroll
    for (int d = 1; d < 64; d <<= 1) s += __shfl_xor(s, d);
    if (lane == 0) wnorm[code] = s;
}

// ---------------- K1: 256x256 8-phase MFMA GEMM + argmin ----------------
// R4 skeleton (schedule & gates verified correct) + fixes:
//  - XCD row-chunk: bid = x + 8*(c + 4*rl) -> per-XCD Xb slice = 4MB (L2),
//    so the counted-vmcnt gates wait on L2 (~200cy) not L3/HBM (R4's bug).
//  - R4's measured-0-conflict LDS forms kept byte-for-byte.
//  - cheap packed-key argmin epilogue (32-col chunks).
// 8 waves (2M x 4N), BK=64, 128KB LDS dbuf. Wave output 128x64 split across
// row-halves (rows wr*64 + mh*128): each quadrant-phase reads one A-half and
// one B-half; tile t+2 lows prefetch into the live buffer after their last
// reader. vmcnt(4) once per tile; vmcnt(0) only at t==NT-2.
__global__ void __launch_bounds__(512, 1)
gemm_argmin(const short* __restrict__ Xb, const short* __restrict__ Wb,
            const float* __restrict__ wnorm, uint32_t* __restrict__ keys) {
    __shared__ __align__(16) short As[2][256 * BK];   // 64 KB
    __shared__ __align__(16) short Bs[2][256 * BK];   // 64 KB

    const int tid  = threadIdx.x;
    const int lane = tid & 63;
    const int wave = tid >> 6;
    const int wr = wave >> 2, wc = wave & 3;
    const int lr = lane & 15, kg = lane >> 4;

    // bid = x + 8*(c + 4*rl): XCD x owns Xb rows [x*4096, x*4096+4096) = 4MB.
    const int bid = blockIdx.x;
    const int colBase = ((bid >> 3) & 3) * 256;          // 4 col-tiles
    const int rowBase = ((bid & 7) * 16 + (bid >> 5)) * 256;  // 128 row-tiles

    // staging: thread -> row sr=tid>>3 (+64), dest slot tid&7, src slot XOR'd
    const int sr = tid >> 3;                       // 0..63
    const int sq = ((tid & 7) ^ (sr & 7)) * 8;     // pre-swizzled source
    const int dq = (tid & 7) * 8;                  // linear LDS dest
    const short* aBase = Xb + (size_t)rowBase * DIM;
    const short* bBase = Wb + (size_t)colBase * DIM;

#define STAGE_A(buf, tt, h) do {                                              \
    gl_lds16(aBase + (size_t)((h)*128 +      sr) * DIM + (tt)*BK + sq,        \
             &As[buf][((h)*128 +      sr)*BK + dq]);                          \
    gl_lds16(aBase + (size_t)((h)*128 + 64 + sr) * DIM + (tt)*BK + sq,        \
             &As[buf][((h)*128 + 64 + sr)*BK + dq]);                          \
  } while (0)
#define STAGE_B(buf, tt, h) do {                                              \
    gl_lds16(bBase + (size_t)((h)*128 +      sr) * DIM + (tt)*BK + sq,        \
             &Bs[buf][((h)*128 +      sr)*BK + dq]);                          \
    gl_lds16(bBase + (size_t)((h)*128 + 64 + sr) * DIM + (tt)*BK + sq,        \
             &Bs[buf][((h)*128 + 64 + sr)*BK + dq]);                          \
  } while (0)

    f32x4 acc[8][4];
    #pragma unroll
    for (int m = 0; m < 8; ++m)
        #pragma unroll
        for (int n = 0; n < 4; ++n) acc[m][n] = (f32x4)0.f;

    // swizzled read slot: logical slot (ks*4+kg) XOR (row&7)=(lr&7)
    const int sF0 = ((0*4 + kg) ^ (lr & 7)) * 8;
    const int sF1 = ((1*4 + kg) ^ (lr & 7)) * 8;
    const int aRow = wr * 64 + lr;   // + mh*128 + mm*16
    const int bRow = wc * 32 + lr;   // + nh*128 + nn*16

    bf16x8 aF[4][2], bF0[2][2], bF1[2][2];

#define LDA(c, mh) do { _Pragma("unroll")                                     \
    for (int mm = 0; mm < 4; ++mm) {                                          \
      aF[mm][0] = __builtin_bit_cast(bf16x8,                                  \
          *(const s16x8*)&As[c][((mh)*128 + aRow + mm*16)*BK + sF0]);         \
      aF[mm][1] = __builtin_bit_cast(bf16x8,                                  \
          *(const s16x8*)&As[c][((mh)*128 + aRow + mm*16)*BK + sF1]); } } while (0)
#define LDB(c, nh, dst) do { _Pragma("unroll")                                \
    for (int nn = 0; nn < 2; ++nn) {                                          \
      dst[nn][0] = __builtin_bit_cast(bf16x8,                                 \
          *(const s16x8*)&Bs[c][((nh)*128 + bRow + nn*16)*BK + sF0]);         \
      dst[nn][1] = __builtin_bit_cast(bf16x8,                                 \
          *(const s16x8*)&Bs[c][((nh)*128 + bRow + nn*16)*BK + sF1]); } } while (0)

#define MFMA_Q(mh, nh, bsrc) do { _Pragma("unroll")                           \
    for (int mm = 0; mm < 4; ++mm) { _Pragma("unroll")                        \
    for (int nn = 0; nn < 2; ++nn) { _Pragma("unroll")                        \
    for (int ks = 0; ks < 2; ++ks)                                            \
      acc[(mh)*4+mm][(nh)*2+nn] = __builtin_amdgcn_mfma_f32_16x16x32_bf16(    \
          aF[mm][ks], bsrc[nn][ks], acc[(mh)*4+mm][(nh)*2+nn], 0,0,0);        \
    } } } while (0)

    // prologue: tile0 all 4 halves + tile1 lows; retire tile0's 8 loads.
    STAGE_A(0, 0, 0); STAGE_B(0, 0, 0); STAGE_A(0, 0, 1); STAGE_B(0, 0, 1);
    STAGE_A(1, 1, 0); STAGE_B(1, 1, 0);
    asm volatile("s_waitcnt vmcnt(4)" ::: "memory");
    __builtin_amdgcn_s_barrier();

    #pragma unroll
    for (int t = 0; t < NT; ++t) {
        const int c = t & 1;
        // P1 (mh0,nh0): read A-low,B-low; stage (t+1) A-high -> other buf.
        LDA(c, 0); LDB(c, 0, bF0);
        if (t + 1 < NT) STAGE_A(c ^ 1, t + 1, 1);
        __builtin_amdgcn_s_barrier();
        asm volatile("s_waitcnt lgkmcnt(0)" ::: "memory");
        __builtin_amdgcn_s_setprio(1); MFMA_Q(0, 0, bF0); __builtin_amdgcn_s_setprio(0);
        __builtin_amdgcn_s_barrier();
        // P2 (mh0,nh1): read B-high (A-low frags reused); stage (t+1) B-high.
        LDB(c, 1, bF1);
        if (t + 1 < NT) STAGE_B(c ^ 1, t + 1, 1);
        __builtin_amdgcn_s_barrier();
        asm volatile("s_waitcnt lgkmcnt(0)" ::: "memory");
        __builtin_amdgcn_s_setprio(1); MFMA_Q(0, 1, bF1); __builtin_amdgcn_s_setprio(0);
        __builtin_amdgcn_s_barrier();
        // P3 (mh1,nh0): read A-high (B-low frags reused); stage (t+2) A-low
        // into live buf (A-low of t last ds_read at P1, 2+ barriers ago).
        LDA(c, 1);
        if (t + 2 < NT) STAGE_A(c, t + 2, 0);
        __builtin_amdgcn_s_barrier();
        asm volatile("s_waitcnt lgkmcnt(0)" ::: "memory");
        __builtin_amdgcn_s_setprio(1); MFMA_Q(1, 0, bF0); __builtin_amdgcn_s_setprio(0);
        __builtin_amdgcn_s_barrier();
        // P4 (mh1,nh1): all frags in regs; stage (t+2) B-low (last read P1).
        if (t + 2 < NT) STAGE_B(c, t + 2, 0);
        __builtin_amdgcn_s_barrier();
        __builtin_amdgcn_s_setprio(1); MFMA_Q(1, 1, bF1); __builtin_amdgcn_s_setprio(0);
        // gate: (t+1) halves landed; (t+2) lows (4 loads) stay in flight.
        if (t < NT - 2)       asm volatile("s_waitcnt vmcnt(4)" ::: "memory");
        else if (t == NT - 2) asm volatile("s_waitcnt vmcnt(0)" ::: "memory");
        __builtin_amdgcn_s_barrier();
    }
#undef STAGE_A
#undef STAGE_B
#undef LDA
#undef LDB
#undef MFMA_Q

    // Epilogue: score = wnorm[col] - 2*dot, packed sortable u32 (col in low
    // 10 bits, tie-break lowest col). 32-col chunks -> keys[row][32].
    float wn[4]; int wcol[4];
    #pragma unroll
    for (int n = 0; n < 4; ++n) {
        wcol[n] = colBase + (n >> 1) * 128 + wc * 32 + (n & 1) * 16 + lr;
        wn[n] = wnorm[wcol[n]];
    }
    const int cb32 = colBase >> 5;
    #pragma unroll
    for (int m = 0; m < 8; ++m) {
        const int rowB = rowBase + (m >> 2) * 128 + wr * 64 + (m & 3) * 16 + kg * 4;
        #pragma unroll
        for (int r = 0; r < 4; ++r) {
            #pragma unroll
            for (int nh = 0; nh < 2; ++nh) {
                uint32_t best = 0xFFFFFFFFu;
                #pragma unroll
                for (int nn = 0; nn < 2; ++nn) {
                    const int n = nh * 2 + nn;
                    float sc = wn[n] - 2.0f * acc[m][n][r];
                    uint32_t u = __float_as_uint(sc);
                    u = (u & 0x80000000u) ? ~u : (u | 0x80000000u);  // sortable
                    uint32_t key = (u & ~1023u) | (uint32_t)wcol[n];
                    best = min(best, key);
                }
                #pragma unroll
                for (int d = 1; d < 16; d <<= 1)
                    best = min(best, (uint32_t)__shfl_xor((int)best, d));
                if (lr == 0)
                    keys[(size_t)(rowB + r) * 32 + cb32 + nh * 4 + wc] = best;
            }
        }
    }
}

// ---------------- K2: min over 32 chunk keys + xnorm -> block partial ----------------
__global__ void __launch_bounds__(256)
reduce_loss(const uint32_t* __restrict__ keys, const float* __restrict__ xnorm,
            float* __restrict__ partial) {
    __shared__ float sm[256];
    const int row = blockIdx.x * 256 + threadIdx.x;
    const uint4* kp = (const uint4*)(keys + (size_t)row * 32);
    uint32_t mk = 0xFFFFFFFFu;
    #pragma unroll
    for (int i = 0; i < 8; ++i) {
        uint4 k = kp[i];
        mk = min(mk, min(min(k.x, k.y), min(k.z, k.w)));
    }
    uint32_t sb = mk & ~1023u;
    float sc = (sb & 0x80000000u) ? __uint_as_float(sb ^ 0x80000000u)
                                  : __uint_as_float(~sb);
    sm[threadIdx.x] = xnorm[row] + sc;   // ||x||^2 + (||w||^2 - 2 x.w)
    __syncthreads();
    for (int st = 128; st > 0; st >>= 1) {
        if (threadIdx.x < st) sm[threadIdx.x] += sm[threadIdx.x + st];
        __syncthreads();
    }
    if (threadIdx.x == 0) partial[blockIdx.x] = sm[0];
}

// ---------------- K3: final mean over 128 partials (double accum) ----------------
__global__ void __launch_bounds__(128)
finalize(const float* __restrict__ partial, float* __restrict__ out) {
    __shared__ double sm[128];
    sm[threadIdx.x] = (double)partial[threadIdx.x];
    __syncthreads();
    for (int st = 64; st > 0; st >>= 1) {
        if (threadIdx.x < st) sm[threadIdx.x] += sm[threadIdx.x + st];
        __syncthreads();
    }
    if (threadIdx.x == 0)
        out[0] = (float)(sm[0] / (double)((size_t)N_ROWS * DIM));
}

extern "C" void kernel_launch(void* const* d_in, const int* in_sizes, int n_in,
                              void* d_out, int out_size, void* d_ws, size_t ws_size,
                              hipStream_t stream) {
    const float* X = (const float*)d_in[0];   // [32768][512]
    const float* W = (const float*)d_in[1];   // [1024][512]
    char* ws = (char*)d_ws;
    short*    Xb      = (short*)ws;                          // 32 MB @ 0
    short*    Wb      = (short*)(ws + 33554432);             // 1 MB
    float*    wnorm   = (float*)(ws + 34603008);             // 4 KB
    float*    xnorm   = (float*)(ws + 34607104);             // 128 KB
    uint32_t* keys    = (uint32_t*)(ws + 34738176);          // 4 MB
    float*    partial = (float*)(ws + 38932480);             // 512 B
    float*    out     = (float*)d_out;

    convertX<<<N_ROWS / 4, 256, 0, stream>>>(X, Xb, xnorm);
    convertW<<<N_CODES / 4, 256, 0, stream>>>(W, Wb, wnorm);
    gemm_argmin<<<512, 512, 0, stream>>>(Xb, Wb, wnorm, keys);
    reduce_loss<<<N_ROWS / 256, 256, 0, stream>>>(keys, xnorm, partial);
    finalize<<<1, 128, 0, stream>>>(partial, out);
}